// Round 8
// baseline (307.219 us; speedup 1.0000x reference)
//
#include <hip/hip_runtime.h>

#define DF 96
#define BN_EPS 1e-5f
#define SLOPE 0.05f
#define LPN 12            // lanes per node in gather
#define GBLK 192          // gather block threads
#define NPBG (GBLK / LPN) // 16 nodes per gather block
#define XPAD 104          // LDS row stride (shorts) for the x2 tile

typedef __attribute__((ext_vector_type(8))) short bf16x8;
typedef __attribute__((ext_vector_type(4))) float f32x4;
typedef __attribute__((ext_vector_type(8))) unsigned short u16x8;

__device__ __forceinline__ unsigned short f2bf(float f) {
    unsigned u = __builtin_bit_cast(unsigned, f);
    return (unsigned short)((u + 0x7FFFu + ((u >> 16) & 1u)) >> 16);
}
__device__ __forceinline__ float bf2f(unsigned short h) {
    return __builtin_bit_cast(float, (unsigned)h << 16);
}

// ---------------- fused prep: BN fold + weight transpose/convert + cnt zero ----
__global__ __launch_bounds__(256) void k_prep(const float* __restrict__ gamma,
                                              const float* __restrict__ beta,
                                              const float* __restrict__ mean,
                                              const float* __restrict__ var,
                                              float* __restrict__ bnscale,
                                              float* __restrict__ bnbias,
                                              const float* __restrict__ W1,
                                              const float* __restrict__ W2,
                                              unsigned short* __restrict__ Wt1,
                                              unsigned short* __restrict__ Wt2,
                                              int* __restrict__ cnt,
                                              int* __restrict__ done, int n) {
    int i = blockIdx.x * 256 + threadIdx.x;
    if (i < DF * DF) {
        int nn = i / DF, k = i - nn * DF;
        Wt1[i] = f2bf(W1[k * DF + nn]);
        Wt2[i] = f2bf(W2[k * DF + nn]);
    }
    if (i < DF) {
        float s = gamma[i] * rsqrtf(var[i] + BN_EPS);
        bnscale[i] = s;
        bnbias[i]  = beta[i] - mean[i] * s;
    }
    if (i == 0) *done = 0;
    if (i < n) cnt[i] = 0;
}

// count in-degree AND record each edge's rank within its dst bucket (2 edges/thread)
__global__ __launch_bounds__(256) void k_countrank(const int* __restrict__ ei,
                                                   int* __restrict__ cnt,
                                                   int* __restrict__ rank, int E) {
    int i = blockIdx.x * 256 + threadIdx.x;
    int e = i * 2;
    if (e + 1 < E) {
        int2 d = *(const int2*)&ei[E + e];
        int r0 = atomicAdd(&cnt[d.x], 1);
        int r1 = atomicAdd(&cnt[d.y], 1);
        *(int2*)&rank[e] = make_int2(r0, r1);
    } else if (e < E) {
        rank[e] = atomicAdd(&cnt[ei[E + e]], 1);
    }
}

// ---------------- single-dispatch exclusive scan of cnt -> rowptr, + dinv ------
// Grid = nb (391) blocks, far below residency capacity -> publish+spin is safe.
__global__ __launch_bounds__(256) void k_scan(const int* __restrict__ cnt,
                                              int* __restrict__ rowptr,
                                              int* __restrict__ bsum,
                                              int* __restrict__ done,
                                              float* __restrict__ dinv,
                                              int n, int E, int nb) {
    __shared__ int sh[256];
    const int t = threadIdx.x;
    const int b = blockIdx.x;
    const int i = b * 256 + t;
    const int x = (i < n) ? cnt[i] : 0;
    sh[t] = x;
    __syncthreads();
#pragma unroll
    for (int off = 1; off < 256; off <<= 1) {
        int v = (t >= off) ? sh[t - off] : 0;
        __syncthreads();
        sh[t] += v;
        __syncthreads();
    }
    const int incl = sh[t];           // inclusive within chunk
    if (t == 255) {
        bsum[b] = incl;               // chunk total
        __threadfence();
        atomicAdd(done, 1);           // publish (device scope)
    }
    if (t == 0) {
        while (__hip_atomic_load(done, __ATOMIC_ACQUIRE, __HIP_MEMORY_SCOPE_AGENT) < nb) {}
    }
    __syncthreads();
    __threadfence();

    // offset = sum of bsum[0..b)  (reduction, not scan)
    int part = 0;
    for (int j = t; j < b; j += 256) part += bsum[j];
    __syncthreads();                  // sh reuse
    sh[t] = part;
    __syncthreads();
#pragma unroll
    for (int s = 128; s > 0; s >>= 1) {
        if (t < s) sh[t] += sh[t + s];
        __syncthreads();
    }
    const int offset = sh[0];

    if (i < n) {
        rowptr[i] = offset + incl - x;            // exclusive
        dinv[i]   = rsqrtf((float)x + 1.0f);      // deg = in-edges + self-loop
    }
    if (i == 0) rowptr[n] = E;
}

// ---------------- GEMM body: hs(bf16) = in @ W * dinv[row] ----------------
// fp32 input path (layer 1). No LDS, no barriers. 4 waves/block, 16 rows/wave.
__device__ __forceinline__ void gemm1_body(int bid, int tid, const float* __restrict__ in,
                                           const unsigned short* __restrict__ Wt,
                                           const float* __restrict__ dinv,
                                           unsigned short* __restrict__ outb, int n) {
    const int wave = tid >> 6;
    const int lane = tid & 63;
    const int l16  = lane & 15;
    const int quad = lane >> 4;
    const int rowbase = bid * 64 + wave * 16;
    const int m = rowbase + l16;
    const bool valid = (m < n);

    bf16x8 bfrag[6][3];
#pragma unroll
    for (int nt = 0; nt < 6; ++nt)
#pragma unroll
        for (int ks = 0; ks < 3; ++ks)
            bfrag[nt][ks] = *(const bf16x8*)&Wt[(nt * 16 + l16) * DF + ks * 32 + quad * 8];

    const float* rowp = in + (size_t)m * DF;
    float4 ra[3][2];
#pragma unroll
    for (int ks = 0; ks < 3; ++ks) {
        if (valid) {
            ra[ks][0] = *(const float4*)&rowp[ks * 32 + quad * 8];
            ra[ks][1] = *(const float4*)&rowp[ks * 32 + quad * 8 + 4];
        } else {
            ra[ks][0] = make_float4(0.f, 0.f, 0.f, 0.f);
            ra[ks][1] = make_float4(0.f, 0.f, 0.f, 0.f);
        }
    }
    bf16x8 afrag[3];
#pragma unroll
    for (int ks = 0; ks < 3; ++ks) {
        const float* a0 = (const float*)&ra[ks][0];
        const float* a1 = (const float*)&ra[ks][1];
        bf16x8 f;
#pragma unroll
        for (int j = 0; j < 4; ++j) {
            f[j]     = (short)f2bf(a0[j]);
            f[j + 4] = (short)f2bf(a1[j]);
        }
        afrag[ks] = f;
    }

    f32x4 acc[6] = {};
#pragma unroll
    for (int ks = 0; ks < 3; ++ks)
#pragma unroll
        for (int nt = 0; nt < 6; ++nt)
            acc[nt] = __builtin_amdgcn_mfma_f32_16x16x32_bf16(afrag[ks], bfrag[nt][ks],
                                                              acc[nt], 0, 0, 0);

#pragma unroll
    for (int reg = 0; reg < 4; ++reg) {
        const int r = rowbase + quad * 4 + reg;
        if (r < n) {
            const float dv = dinv[r];
#pragma unroll
            for (int nt = 0; nt < 6; ++nt)
                outb[(size_t)r * DF + nt * 16 + l16] = f2bf(acc[nt][reg] * dv);
        }
    }
}

// atomic-free CSR fill body: position = rowptr[dst] + rank[e]
__device__ __forceinline__ void fill_body(int bid, int tid, const int* __restrict__ ei,
                                          const int* __restrict__ rowptr,
                                          const int* __restrict__ rank,
                                          int* __restrict__ csr, int E) {
    int e = bid * 256 + tid;
    if (e < E) {
        int src = ei[e];
        int dst = ei[E + e];
        csr[rowptr[dst] + rank[e]] = src;
    }
}

// fused: blocks [0, gb) run GEMM layer-1, blocks [gb, ...) run CSR fill.
__global__ __launch_bounds__(256) void k_gemm1_fill(const float* __restrict__ in,
                                                    const unsigned short* __restrict__ Wt1,
                                                    const float* __restrict__ dinv,
                                                    unsigned short* __restrict__ bufA,
                                                    int n, int gb,
                                                    const int* __restrict__ ei,
                                                    const int* __restrict__ rowptr,
                                                    const int* __restrict__ rank,
                                                    int* __restrict__ csr, int E) {
    const int b = blockIdx.x;
    if (b < gb) gemm1_body(b, threadIdx.x, in, Wt1, dinv, bufA, n);
    else        fill_body(b - gb, threadIdx.x, ei, rowptr, rank, csr, E);
}

// ---------------- fused gather-0 + GEMM-2 ----------------
// Per block: 16 nodes. Phase 1 (all 192 threads): CSR gather of hs1, apply
// layer-1 epilogue (dinv*agg + b1 -> LeakyReLU -> BN), write x2 tile to LDS.
// Phase 2 (wave 0): 16x96 GEMM x2 @ W2, scale by dinv[row], write hs2 to outb.
__global__ __launch_bounds__(GBLK) void k_gather0_gemm2(const int* __restrict__ rowptr,
                                                        const int* __restrict__ csr,
                                                        const unsigned short* __restrict__ hs,
                                                        const float* __restrict__ dinv,
                                                        const float* __restrict__ b1,
                                                        const float* __restrict__ bnscale,
                                                        const float* __restrict__ bnbias,
                                                        const unsigned short* __restrict__ Wt2,
                                                        unsigned short* __restrict__ outb,
                                                        int n) {
    __shared__ unsigned short sx[NPBG * XPAD];
    const int t  = threadIdx.x;
    const int vl = t / LPN;
    const int q  = t % LPN;          // owns bf16 cols [8q, 8q+8)
    const int v  = blockIdx.x * NPBG + vl;

    if (v < n) {
        float acc[8];
        {
            const u16x8 h0 = *(const u16x8*)&hs[(size_t)v * DF + q * 8];  // self-loop
#pragma unroll
            for (int i = 0; i < 8; ++i) acc[i] = bf2f(h0[i]);
        }
        const int e1 = rowptr[v + 1];
        int e = rowptr[v];
        for (; e + 8 <= e1; e += 8) {
            int s[8];
#pragma unroll
            for (int u = 0; u < 8; ++u) s[u] = csr[e + u];
            u16x8 m[8];
#pragma unroll
            for (int u = 0; u < 8; ++u) m[u] = *(const u16x8*)&hs[(size_t)s[u] * DF + q * 8];
#pragma unroll
            for (int u = 0; u < 8; ++u)
#pragma unroll
                for (int i = 0; i < 8; ++i) acc[i] += bf2f(m[u][i]);
        }
        for (; e + 4 <= e1; e += 4) {
            int s[4];
#pragma unroll
            for (int u = 0; u < 4; ++u) s[u] = csr[e + u];
            u16x8 m[4];
#pragma unroll
            for (int u = 0; u < 4; ++u) m[u] = *(const u16x8*)&hs[(size_t)s[u] * DF + q * 8];
#pragma unroll
            for (int u = 0; u < 4; ++u)
#pragma unroll
                for (int i = 0; i < 8; ++i) acc[i] += bf2f(m[u][i]);
        }
        for (; e < e1; ++e) {
            const int s = csr[e];
            const u16x8 m = *(const u16x8*)&hs[(size_t)s * DF + q * 8];
#pragma unroll
            for (int i = 0; i < 8; ++i) acc[i] += bf2f(m[i]);
        }

        const float dv = dinv[v];
        u16x8 o;
#pragma unroll
        for (int i = 0; i < 8; ++i) {
            const int c = q * 8 + i;
            float x = __builtin_fmaf(dv, acc[i], b1[c]);
            x = (x >= 0.f) ? x : SLOPE * x;
            o[i] = f2bf(__builtin_fmaf(x, bnscale[c], bnbias[c]));
        }
        *(u16x8*)&sx[vl * XPAD + q * 8] = o;
    }
    __syncthreads();

    if (t < 64) {
        const int l16  = t & 15;
        const int quad = t >> 4;
        bf16x8 afrag[3];
#pragma unroll
        for (int ks = 0; ks < 3; ++ks)
            afrag[ks] = *(const bf16x8*)&sx[l16 * XPAD + ks * 32 + quad * 8];

        bf16x8 bfrag[6][3];
#pragma unroll
        for (int nt = 0; nt < 6; ++nt)
#pragma unroll
            for (int ks = 0; ks < 3; ++ks)
                bfrag[nt][ks] = *(const bf16x8*)&Wt2[(nt * 16 + l16) * DF + ks * 32 + quad * 8];

        f32x4 acc2[6] = {};
#pragma unroll
        for (int ks = 0; ks < 3; ++ks)
#pragma unroll
            for (int nt = 0; nt < 6; ++nt)
                acc2[nt] = __builtin_amdgcn_mfma_f32_16x16x32_bf16(afrag[ks], bfrag[nt][ks],
                                                                   acc2[nt], 0, 0, 0);

        const int rowbase = blockIdx.x * NPBG;
#pragma unroll
        for (int reg = 0; reg < 4; ++reg) {
            const int r = rowbase + quad * 4 + reg;
            if (r < n) {
                const float dv = dinv[r];
#pragma unroll
                for (int nt = 0; nt < 6; ++nt)
                    outb[(size_t)r * DF + nt * 16 + l16] = f2bf(acc2[nt][reg] * dv);
            }
        }
    }
}

// ---------------- final CSR gather: out(fp32) = dinv[v]*(self+sum) + b2 --------
__global__ __launch_bounds__(GBLK) void k_gather_final(const int* __restrict__ rowptr,
                                                       const int* __restrict__ csr,
                                                       const unsigned short* __restrict__ hs,
                                                       const float* __restrict__ dinv,
                                                       const float* __restrict__ b2,
                                                       float* __restrict__ outp, int n) {
    const int t = threadIdx.x;
    const int v = blockIdx.x * NPBG + t / LPN;
    const int q = t % LPN;
    if (v >= n) return;

    float acc[8];
    {
        const u16x8 h0 = *(const u16x8*)&hs[(size_t)v * DF + q * 8];  // self-loop
#pragma unroll
        for (int i = 0; i < 8; ++i) acc[i] = bf2f(h0[i]);
    }
    const int e1 = rowptr[v + 1];
    int e = rowptr[v];
    for (; e + 8 <= e1; e += 8) {
        int s[8];
#pragma unroll
        for (int u = 0; u < 8; ++u) s[u] = csr[e + u];
        u16x8 m[8];
#pragma unroll
        for (int u = 0; u < 8; ++u) m[u] = *(const u16x8*)&hs[(size_t)s[u] * DF + q * 8];
#pragma unroll
        for (int u = 0; u < 8; ++u)
#pragma unroll
            for (int i = 0; i < 8; ++i) acc[i] += bf2f(m[u][i]);
    }
    for (; e + 4 <= e1; e += 4) {
        int s[4];
#pragma unroll
        for (int u = 0; u < 4; ++u) s[u] = csr[e + u];
        u16x8 m[4];
#pragma unroll
        for (int u = 0; u < 4; ++u) m[u] = *(const u16x8*)&hs[(size_t)s[u] * DF + q * 8];
#pragma unroll
        for (int u = 0; u < 4; ++u)
#pragma unroll
            for (int i = 0; i < 8; ++i) acc[i] += bf2f(m[u][i]);
    }
    for (; e < e1; ++e) {
        const int s = csr[e];
        const u16x8 m = *(const u16x8*)&hs[(size_t)s * DF + q * 8];
#pragma unroll
        for (int i = 0; i < 8; ++i) acc[i] += bf2f(m[i]);
    }

    const float dv = dinv[v];
    float* op = (float*)outp + (size_t)v * DF + q * 8;
    float4 o0, o1;
    o0.x = __builtin_fmaf(acc[0], dv, b2[q * 8 + 0]);
    o0.y = __builtin_fmaf(acc[1], dv, b2[q * 8 + 1]);
    o0.z = __builtin_fmaf(acc[2], dv, b2[q * 8 + 2]);
    o0.w = __builtin_fmaf(acc[3], dv, b2[q * 8 + 3]);
    o1.x = __builtin_fmaf(acc[4], dv, b2[q * 8 + 4]);
    o1.y = __builtin_fmaf(acc[5], dv, b2[q * 8 + 5]);
    o1.z = __builtin_fmaf(acc[6], dv, b2[q * 8 + 6]);
    o1.w = __builtin_fmaf(acc[7], dv, b2[q * 8 + 7]);
    *(float4*)op       = o0;
    *(float4*)(op + 4) = o1;
}

extern "C" void kernel_launch(void* const* d_in, const int* in_sizes, int n_in,
                              void* d_out, int out_size, void* d_ws, size_t ws_size,
                              hipStream_t stream) {
    const float* node_feat = (const float*)d_in[0];
    const int*   ei        = (const int*)d_in[1];
    const float* W1        = (const float*)d_in[2];
    const float* b1        = (const float*)d_in[3];
    const float* W2        = (const float*)d_in[4];
    const float* b2        = (const float*)d_in[5];
    const float* gamma     = (const float*)d_in[6];
    const float* beta      = (const float*)d_in[7];
    const float* mean      = (const float*)d_in[8];
    const float* var       = (const float*)d_in[9];

    const int n  = in_sizes[0] / DF;  // 100000
    const int E  = in_sizes[1] / 2;   // 800000
    const int nb = (n + 255) / 256;   // 391

    char* base = (char*)d_ws;
    size_t off = 0;
    auto alloc = [&](size_t bytes) { void* p = base + off; off = (off + bytes + 15) & ~(size_t)15; return p; };
    int*   cnt     = (int*)alloc(sizeof(int) * n);
    int*   rowptr  = (int*)alloc(sizeof(int) * (n + 1));
    int*   bsum    = (int*)alloc(sizeof(int) * 512);
    int*   done    = (int*)alloc(sizeof(int) * 16);
    float* dinv    = (float*)alloc(sizeof(float) * n);
    float* bnscale = (float*)alloc(sizeof(float) * DF);
    float* bnbias  = (float*)alloc(sizeof(float) * DF);
    unsigned short* Wt1 = (unsigned short*)alloc(sizeof(short) * DF * DF);
    unsigned short* Wt2 = (unsigned short*)alloc(sizeof(short) * DF * DF);
    int*   rank    = (int*)alloc(sizeof(int) * E);
    int*   csr     = (int*)alloc(sizeof(int) * E);
    unsigned short* bufA = (unsigned short*)alloc(sizeof(short) * (size_t)n * DF); // hs1
    unsigned short* bufB = (unsigned short*)alloc(sizeof(short) * (size_t)n * DF); // hs2
    float* out     = (float*)d_out;

    // prep + CSR build
    k_prep<<<nb, 256, 0, stream>>>(gamma, beta, mean, var, bnscale, bnbias,
                                   W1, W2, Wt1, Wt2, cnt, done, n);
    k_countrank<<<(E / 2 + 255) / 256, 256, 0, stream>>>(ei, cnt, rank, E);
    k_scan<<<nb, 256, 0, stream>>>(cnt, rowptr, bsum, done, dinv, n, E, nb);

    const int gb = (n + 63) / 64;            // gemm blocks
    const int fb = (E + 255) / 256;          // fill blocks
    const int gg = (n + NPBG - 1) / NPBG;    // gather blocks

    // layer 1 GEMM overlapped with CSR fill (independent after scan)
    k_gemm1_fill<<<gb + fb, 256, 0, stream>>>(node_feat, Wt1, dinv, bufA, n, gb,
                                              ei, rowptr, rank, csr, E);
    // gather-0 + layer-2 GEMM fused (x2 never materialized): bufA -> bufB
    k_gather0_gemm2<<<gg, GBLK, 0, stream>>>(rowptr, csr, bufA, dinv, b1, bnscale,
                                             bnbias, Wt2, bufB, n);
    // final gather + epilogue: bufB -> out
    k_gather_final<<<gg, GBLK, 0, stream>>>(rowptr, csr, bufB, dinv, b2, out, n);
}

// Round 9
// 251.164 us; speedup vs baseline: 1.2232x; 1.2232x over previous
//
#include <hip/hip_runtime.h>

#define DF 96
#define BN_EPS 1e-5f
#define SLOPE 0.05f
#define LPN 12            // lanes per node in gather
#define GBLK 192          // gather block threads
#define NPBG (GBLK / LPN) // 16 nodes per gather block
#define XPAD 104          // LDS row stride (shorts) for the x2 tile

typedef __attribute__((ext_vector_type(8))) short bf16x8;
typedef __attribute__((ext_vector_type(4))) float f32x4;
typedef __attribute__((ext_vector_type(8))) unsigned short u16x8;

__device__ __forceinline__ unsigned short f2bf(float f) {
    unsigned u = __builtin_bit_cast(unsigned, f);
    return (unsigned short)((u + 0x7FFFu + ((u >> 16) & 1u)) >> 16);
}
__device__ __forceinline__ float bf2f(unsigned short h) {
    return __builtin_bit_cast(float, (unsigned)h << 16);
}

// ---------------- fused prep: BN fold + weight transpose/convert + cnt zero ----
__global__ __launch_bounds__(256) void k_prep(const float* __restrict__ gamma,
                                              const float* __restrict__ beta,
                                              const float* __restrict__ mean,
                                              const float* __restrict__ var,
                                              float* __restrict__ bnscale,
                                              float* __restrict__ bnbias,
                                              const float* __restrict__ W1,
                                              const float* __restrict__ W2,
                                              unsigned short* __restrict__ Wt1,
                                              unsigned short* __restrict__ Wt2,
                                              int* __restrict__ cnt, int n) {
    int i = blockIdx.x * 256 + threadIdx.x;
    if (i < DF * DF) {
        int nn = i / DF, k = i - nn * DF;
        Wt1[i] = f2bf(W1[k * DF + nn]);
        Wt2[i] = f2bf(W2[k * DF + nn]);
    }
    if (i < DF) {
        float s = gamma[i] * rsqrtf(var[i] + BN_EPS);
        bnscale[i] = s;
        bnbias[i]  = beta[i] - mean[i] * s;
    }
    if (i < n) cnt[i] = 0;
}

// count in-degree AND record each edge's rank within its dst bucket (2 edges/thread)
__global__ __launch_bounds__(256) void k_countrank(const int* __restrict__ ei,
                                                   int* __restrict__ cnt,
                                                   int* __restrict__ rank, int E) {
    int i = blockIdx.x * 256 + threadIdx.x;
    int e = i * 2;
    if (e + 1 < E) {
        int2 d = *(const int2*)&ei[E + e];
        int r0 = atomicAdd(&cnt[d.x], 1);
        int r1 = atomicAdd(&cnt[d.y], 1);
        *(int2*)&rank[e] = make_int2(r0, r1);
    } else if (e < E) {
        rank[e] = atomicAdd(&cnt[ei[E + e]], 1);
    }
}

// per-256-chunk exclusive scan of cnt -> rowptr (pre-offset), chunk totals -> bsum
__global__ __launch_bounds__(256) void k_scan1(const int* __restrict__ cnt,
                                               int* __restrict__ rowptr,
                                               int* __restrict__ bsum, int n) {
    __shared__ int sh[256];
    int t = threadIdx.x;
    int i = blockIdx.x * 256 + t;
    int x = (i < n) ? cnt[i] : 0;
    sh[t] = x;
    __syncthreads();
#pragma unroll
    for (int off = 1; off < 256; off <<= 1) {
        int v = (t >= off) ? sh[t - off] : 0;
        __syncthreads();
        sh[t] += v;
        __syncthreads();
    }
    if (i < n) rowptr[i] = sh[t] - x;
    if (t == 255) bsum[blockIdx.x] = sh[255];
}

// every block redundantly scans bsum in LDS, then finalizes rowptr + dinv
__global__ __launch_bounds__(512) void k_scan23(int* __restrict__ rowptr,
                                                const int* __restrict__ bsum,
                                                const int* __restrict__ cnt,
                                                float* __restrict__ dinv,
                                                int n, int E, int nb) {
    __shared__ int sh[512];
    __shared__ int sbex[512];
    const int t = threadIdx.x;
    int x = (t < nb) ? bsum[t] : 0;
    sh[t] = x;
    __syncthreads();
#pragma unroll
    for (int off = 1; off < 512; off <<= 1) {
        int v = (t >= off) ? sh[t - off] : 0;
        __syncthreads();
        sh[t] += v;
        __syncthreads();
    }
    sbex[t] = sh[t] - x;   // exclusive chunk offsets
    __syncthreads();

    const int i = blockIdx.x * 512 + t;
    if (i < n) {
        rowptr[i] = rowptr[i] + sbex[i >> 8];
        dinv[i]   = rsqrtf((float)cnt[i] + 1.0f);
    }
    if (i == 0) rowptr[n] = E;
}

// ---------------- GEMM body: hs(bf16) = in @ W * dinv[row] ----------------
// fp32 input path (layer 1). No LDS, no barriers. 4 waves/block, 16 rows/wave.
__device__ __forceinline__ void gemm1_body(int bid, int tid, const float* __restrict__ in,
                                           const unsigned short* __restrict__ Wt,
                                           const float* __restrict__ dinv,
                                           unsigned short* __restrict__ outb, int n) {
    const int wave = tid >> 6;
    const int lane = tid & 63;
    const int l16  = lane & 15;
    const int quad = lane >> 4;
    const int rowbase = bid * 64 + wave * 16;
    const int m = rowbase + l16;
    const bool valid = (m < n);

    bf16x8 bfrag[6][3];
#pragma unroll
    for (int nt = 0; nt < 6; ++nt)
#pragma unroll
        for (int ks = 0; ks < 3; ++ks)
            bfrag[nt][ks] = *(const bf16x8*)&Wt[(nt * 16 + l16) * DF + ks * 32 + quad * 8];

    const float* rowp = in + (size_t)m * DF;
    float4 ra[3][2];
#pragma unroll
    for (int ks = 0; ks < 3; ++ks) {
        if (valid) {
            ra[ks][0] = *(const float4*)&rowp[ks * 32 + quad * 8];
            ra[ks][1] = *(const float4*)&rowp[ks * 32 + quad * 8 + 4];
        } else {
            ra[ks][0] = make_float4(0.f, 0.f, 0.f, 0.f);
            ra[ks][1] = make_float4(0.f, 0.f, 0.f, 0.f);
        }
    }
    bf16x8 afrag[3];
#pragma unroll
    for (int ks = 0; ks < 3; ++ks) {
        const float* a0 = (const float*)&ra[ks][0];
        const float* a1 = (const float*)&ra[ks][1];
        bf16x8 f;
#pragma unroll
        for (int j = 0; j < 4; ++j) {
            f[j]     = (short)f2bf(a0[j]);
            f[j + 4] = (short)f2bf(a1[j]);
        }
        afrag[ks] = f;
    }

    f32x4 acc[6] = {};
#pragma unroll
    for (int ks = 0; ks < 3; ++ks)
#pragma unroll
        for (int nt = 0; nt < 6; ++nt)
            acc[nt] = __builtin_amdgcn_mfma_f32_16x16x32_bf16(afrag[ks], bfrag[nt][ks],
                                                              acc[nt], 0, 0, 0);

#pragma unroll
    for (int reg = 0; reg < 4; ++reg) {
        const int r = rowbase + quad * 4 + reg;
        if (r < n) {
            const float dv = dinv[r];
#pragma unroll
            for (int nt = 0; nt < 6; ++nt)
                outb[(size_t)r * DF + nt * 16 + l16] = f2bf(acc[nt][reg] * dv);
        }
    }
}

// atomic-free CSR fill body: position = rowptr[dst] + rank[e]
__device__ __forceinline__ void fill_body(int bid, int tid, const int* __restrict__ ei,
                                          const int* __restrict__ rowptr,
                                          const int* __restrict__ rank,
                                          int* __restrict__ csr, int E) {
    int e = bid * 256 + tid;
    if (e < E) {
        int src = ei[e];
        int dst = ei[E + e];
        csr[rowptr[dst] + rank[e]] = src;
    }
}

// fused: blocks [0, gb) run GEMM layer-1, blocks [gb, ...) run CSR fill.
__global__ __launch_bounds__(256) void k_gemm1_fill(const float* __restrict__ in,
                                                    const unsigned short* __restrict__ Wt1,
                                                    const float* __restrict__ dinv,
                                                    unsigned short* __restrict__ bufA,
                                                    int n, int gb,
                                                    const int* __restrict__ ei,
                                                    const int* __restrict__ rowptr,
                                                    const int* __restrict__ rank,
                                                    int* __restrict__ csr, int E) {
    const int b = blockIdx.x;
    if (b < gb) gemm1_body(b, threadIdx.x, in, Wt1, dinv, bufA, n);
    else        fill_body(b - gb, threadIdx.x, ei, rowptr, rank, csr, E);
}

// ---------------- fused gather-0 + GEMM-2 ----------------
// Per block: 16 nodes. Phase 1 (all 192 threads): CSR gather of hs1, apply
// layer-1 epilogue (dinv*agg + b1 -> LeakyReLU -> BN), write x2 tile to LDS.
// Phase 2 (wave 0): 16x96 GEMM x2 @ W2, scale by dinv[row], write hs2 to outb.
__global__ __launch_bounds__(GBLK) void k_gather0_gemm2(const int* __restrict__ rowptr,
                                                        const int* __restrict__ csr,
                                                        const unsigned short* __restrict__ hs,
                                                        const float* __restrict__ dinv,
                                                        const float* __restrict__ b1,
                                                        const float* __restrict__ bnscale,
                                                        const float* __restrict__ bnbias,
                                                        const unsigned short* __restrict__ Wt2,
                                                        unsigned short* __restrict__ outb,
                                                        int n) {
    __shared__ unsigned short sx[NPBG * XPAD];
    const int t  = threadIdx.x;
    const int vl = t / LPN;
    const int q  = t % LPN;          // owns bf16 cols [8q, 8q+8)
    const int v  = blockIdx.x * NPBG + vl;

    if (v < n) {
        float acc[8];
        {
            const u16x8 h0 = *(const u16x8*)&hs[(size_t)v * DF + q * 8];  // self-loop
#pragma unroll
            for (int i = 0; i < 8; ++i) acc[i] = bf2f(h0[i]);
        }
        const int e1 = rowptr[v + 1];
        int e = rowptr[v];
        for (; e + 8 <= e1; e += 8) {
            int s[8];
#pragma unroll
            for (int u = 0; u < 8; ++u) s[u] = csr[e + u];
            u16x8 m[8];
#pragma unroll
            for (int u = 0; u < 8; ++u) m[u] = *(const u16x8*)&hs[(size_t)s[u] * DF + q * 8];
#pragma unroll
            for (int u = 0; u < 8; ++u)
#pragma unroll
                for (int i = 0; i < 8; ++i) acc[i] += bf2f(m[u][i]);
        }
        for (; e + 4 <= e1; e += 4) {
            int s[4];
#pragma unroll
            for (int u = 0; u < 4; ++u) s[u] = csr[e + u];
            u16x8 m[4];
#pragma unroll
            for (int u = 0; u < 4; ++u) m[u] = *(const u16x8*)&hs[(size_t)s[u] * DF + q * 8];
#pragma unroll
            for (int u = 0; u < 4; ++u)
#pragma unroll
                for (int i = 0; i < 8; ++i) acc[i] += bf2f(m[u][i]);
        }
        for (; e < e1; ++e) {
            const int s = csr[e];
            const u16x8 m = *(const u16x8*)&hs[(size_t)s * DF + q * 8];
#pragma unroll
            for (int i = 0; i < 8; ++i) acc[i] += bf2f(m[i]);
        }

        const float dv = dinv[v];
        u16x8 o;
#pragma unroll
        for (int i = 0; i < 8; ++i) {
            const int c = q * 8 + i;
            float x = __builtin_fmaf(dv, acc[i], b1[c]);
            x = (x >= 0.f) ? x : SLOPE * x;
            o[i] = f2bf(__builtin_fmaf(x, bnscale[c], bnbias[c]));
        }
        *(u16x8*)&sx[vl * XPAD + q * 8] = o;
    }
    __syncthreads();

    if (t < 64) {
        const int l16  = t & 15;
        const int quad = t >> 4;
        bf16x8 afrag[3];
#pragma unroll
        for (int ks = 0; ks < 3; ++ks)
            afrag[ks] = *(const bf16x8*)&sx[l16 * XPAD + ks * 32 + quad * 8];

        bf16x8 bfrag[6][3];
#pragma unroll
        for (int nt = 0; nt < 6; ++nt)
#pragma unroll
            for (int ks = 0; ks < 3; ++ks)
                bfrag[nt][ks] = *(const bf16x8*)&Wt2[(nt * 16 + l16) * DF + ks * 32 + quad * 8];

        f32x4 acc2[6] = {};
#pragma unroll
        for (int ks = 0; ks < 3; ++ks)
#pragma unroll
            for (int nt = 0; nt < 6; ++nt)
                acc2[nt] = __builtin_amdgcn_mfma_f32_16x16x32_bf16(afrag[ks], bfrag[nt][ks],
                                                                   acc2[nt], 0, 0, 0);

        const int rowbase = blockIdx.x * NPBG;
#pragma unroll
        for (int reg = 0; reg < 4; ++reg) {
            const int r = rowbase + quad * 4 + reg;
            if (r < n) {
                const float dv = dinv[r];
#pragma unroll
                for (int nt = 0; nt < 6; ++nt)
                    outb[(size_t)r * DF + nt * 16 + l16] = f2bf(acc2[nt][reg] * dv);
            }
        }
    }
}

// ---------------- final CSR gather: out(fp32) = dinv[v]*(self+sum) + b2 --------
__global__ __launch_bounds__(GBLK) void k_gather_final(const int* __restrict__ rowptr,
                                                       const int* __restrict__ csr,
                                                       const unsigned short* __restrict__ hs,
                                                       const float* __restrict__ dinv,
                                                       const float* __restrict__ b2,
                                                       float* __restrict__ outp, int n) {
    const int t = threadIdx.x;
    const int v = blockIdx.x * NPBG + t / LPN;
    const int q = t % LPN;
    if (v >= n) return;

    float acc[8];
    {
        const u16x8 h0 = *(const u16x8*)&hs[(size_t)v * DF + q * 8];  // self-loop
#pragma unroll
        for (int i = 0; i < 8; ++i) acc[i] = bf2f(h0[i]);
    }
    const int e1 = rowptr[v + 1];
    int e = rowptr[v];
    for (; e + 8 <= e1; e += 8) {
        int s[8];
#pragma unroll
        for (int u = 0; u < 8; ++u) s[u] = csr[e + u];
        u16x8 m[8];
#pragma unroll
        for (int u = 0; u < 8; ++u) m[u] = *(const u16x8*)&hs[(size_t)s[u] * DF + q * 8];
#pragma unroll
        for (int u = 0; u < 8; ++u)
#pragma unroll
            for (int i = 0; i < 8; ++i) acc[i] += bf2f(m[u][i]);
    }
    for (; e + 4 <= e1; e += 4) {
        int s[4];
#pragma unroll
        for (int u = 0; u < 4; ++u) s[u] = csr[e + u];
        u16x8 m[4];
#pragma unroll
        for (int u = 0; u < 4; ++u) m[u] = *(const u16x8*)&hs[(size_t)s[u] * DF + q * 8];
#pragma unroll
        for (int u = 0; u < 4; ++u)
#pragma unroll
            for (int i = 0; i < 8; ++i) acc[i] += bf2f(m[u][i]);
    }
    for (; e < e1; ++e) {
        const int s = csr[e];
        const u16x8 m = *(const u16x8*)&hs[(size_t)s * DF + q * 8];
#pragma unroll
        for (int i = 0; i < 8; ++i) acc[i] += bf2f(m[i]);
    }

    const float dv = dinv[v];
    float* op = (float*)outp + (size_t)v * DF + q * 8;
    float4 o0, o1;
    o0.x = __builtin_fmaf(acc[0], dv, b2[q * 8 + 0]);
    o0.y = __builtin_fmaf(acc[1], dv, b2[q * 8 + 1]);
    o0.z = __builtin_fmaf(acc[2], dv, b2[q * 8 + 2]);
    o0.w = __builtin_fmaf(acc[3], dv, b2[q * 8 + 3]);
    o1.x = __builtin_fmaf(acc[4], dv, b2[q * 8 + 4]);
    o1.y = __builtin_fmaf(acc[5], dv, b2[q * 8 + 5]);
    o1.z = __builtin_fmaf(acc[6], dv, b2[q * 8 + 6]);
    o1.w = __builtin_fmaf(acc[7], dv, b2[q * 8 + 7]);
    *(float4*)op       = o0;
    *(float4*)(op + 4) = o1;
}

extern "C" void kernel_launch(void* const* d_in, const int* in_sizes, int n_in,
                              void* d_out, int out_size, void* d_ws, size_t ws_size,
                              hipStream_t stream) {
    const float* node_feat = (const float*)d_in[0];
    const int*   ei        = (const int*)d_in[1];
    const float* W1        = (const float*)d_in[2];
    const float* b1        = (const float*)d_in[3];
    const float* W2        = (const float*)d_in[4];
    const float* b2        = (const float*)d_in[5];
    const float* gamma     = (const float*)d_in[6];
    const float* beta      = (const float*)d_in[7];
    const float* mean      = (const float*)d_in[8];
    const float* var       = (const float*)d_in[9];

    const int n  = in_sizes[0] / DF;  // 100000
    const int E  = in_sizes[1] / 2;   // 800000
    const int nb = (n + 255) / 256;   // 391

    char* base = (char*)d_ws;
    size_t off = 0;
    auto alloc = [&](size_t bytes) { void* p = base + off; off = (off + bytes + 15) & ~(size_t)15; return p; };
    int*   cnt     = (int*)alloc(sizeof(int) * n);
    int*   rowptr  = (int*)alloc(sizeof(int) * (n + 1));
    int*   bsum    = (int*)alloc(sizeof(int) * 512);
    float* dinv    = (float*)alloc(sizeof(float) * n);
    float* bnscale = (float*)alloc(sizeof(float) * DF);
    float* bnbias  = (float*)alloc(sizeof(float) * DF);
    unsigned short* Wt1 = (unsigned short*)alloc(sizeof(short) * DF * DF);
    unsigned short* Wt2 = (unsigned short*)alloc(sizeof(short) * DF * DF);
    int*   rank    = (int*)alloc(sizeof(int) * E);
    int*   csr     = (int*)alloc(sizeof(int) * E);
    unsigned short* bufA = (unsigned short*)alloc(sizeof(short) * (size_t)n * DF); // hs1
    unsigned short* bufB = (unsigned short*)alloc(sizeof(short) * (size_t)n * DF); // hs2
    float* out     = (float*)d_out;

    // prep + CSR build
    k_prep<<<nb, 256, 0, stream>>>(gamma, beta, mean, var, bnscale, bnbias,
                                   W1, W2, Wt1, Wt2, cnt, n);
    k_countrank<<<(E / 2 + 255) / 256, 256, 0, stream>>>(ei, cnt, rank, E);
    k_scan1<<<nb, 256, 0, stream>>>(cnt, rowptr, bsum, n);
    k_scan23<<<(n + 511) / 512, 512, 0, stream>>>(rowptr, bsum, cnt, dinv, n, E, nb);

    const int gb = (n + 63) / 64;            // gemm blocks
    const int fb = (E + 255) / 256;          // fill blocks
    const int gg = (n + NPBG - 1) / NPBG;    // gather blocks

    // layer 1 GEMM overlapped with CSR fill (independent after scan)
    k_gemm1_fill<<<gb + fb, 256, 0, stream>>>(node_feat, Wt1, dinv, bufA, n, gb,
                                              ei, rowptr, rank, csr, E);
    // gather-0 + layer-2 GEMM fused (x2 never materialized): bufA -> bufB
    k_gather0_gemm2<<<gg, GBLK, 0, stream>>>(rowptr, csr, bufA, dinv, b1, bnscale,
                                             bnbias, Wt2, bufB, n);
    // final gather + epilogue: bufB -> out
    k_gather_final<<<gg, GBLK, 0, stream>>>(rowptr, csr, bufB, dinv, b2, out, n);
}